// Round 9
// baseline (944752.246 us; speedup 1.0000x reference)
//
#include <hip/hip_runtime.h>
#include <cfloat>
#include <cmath>

#define E      512
#define FOURE  2048
#define VT     50000
#define SLEN   128
#define TLEN   129            // decoder steps (targets + EOS)
#define NSTEPS 257
#define NB     64             // workers: the 64 blocks resident on block0's XCD
#define NGRID  512            // 512 blocks x (2/CU residency) => exactly 64 per XCD
#define NCHUNK 196
#define TPAD   132

// ---- workspace layout (bytes); total 2,121,728 <= 2,597,572 proven (r1) ----
#define INBOX_OFF  0            // u64 inbox[2][512] = 8192 (single copy, in-L2)
#define REG_OFF    8192         // election state (128 B)
#define ZERO_BYTES 8320
#define GXE_OFF    16384        // 128*2048 f32 = 1048576 -> ends 1064960
#define PM_OFF     16384        //   alias GxE head (c1 runs after lstm): 103488
#define PS_OFF     119872       //   103488
#define TL_OFF     223360       //   129 f32 -> ends 223876
#define HALL_OFF   540672       //   alias GxE rows 64..96 (dead in decode): 264192 -> ends 804864
#define GXD_OFF    1064960      // 129*2048 f32 = 1056768 -> ends 2121728

__device__ __forceinline__ float sigf(float x){ return 1.0f/(1.0f+__expf(-x)); }
__device__ __forceinline__ float tanhf_fast(float x){ return 2.f*sigf(2.f*x) - 1.f; }

// =================== A: Gx[t][r] = x_t @ W_ih^T + b_ih + b_hh ===================
__global__ __launch_bounds__(256) void gx_kernel(
    const int* __restrict__ src, const int* __restrict__ tgt,
    const float* __restrict__ Wx, const float* __restrict__ Wy,
    const float* __restrict__ encWih, const float* __restrict__ encBih, const float* __restrict__ encBhh,
    const float* __restrict__ decWih, const float* __restrict__ decBih, const float* __restrict__ decBhh,
    float* __restrict__ GxE, float* __restrict__ GxD)
{
  __shared__ float xs[8][E];
  const int tid  = threadIdx.x;
  const int tile = blockIdx.x;
  const bool is_dec = tile >= 16;
  const int t0 = is_dec ? (tile-16)*8 : tile*8;
  const int T  = is_dec ? TLEN : SLEN;

  for (int tt=0; tt<8; ++tt){
    int t = t0+tt;
    if (t < T){
      const float* xrow;
      if (is_dec) xrow = (t==0) ? (Wx + (size_t)1*E) : (Wy + (size_t)tgt[t-1]*E);
      else        xrow = Wx + (size_t)src[t]*E;
      xs[tt][tid]     = xrow[tid];
      xs[tt][tid+256] = xrow[tid+256];
    }
  }
  __syncthreads();

  const int r = blockIdx.y*256 + tid;
  const float* wrow = (is_dec ? decWih : encWih) + (size_t)r*E;
  const float  bias = is_dec ? (decBih[r]+decBhh[r]) : (encBih[r]+encBhh[r]);
  float acc[8];
  #pragma unroll
  for (int i=0;i<8;++i) acc[i]=0.f;

  for (int kc=0; kc<E; kc+=4){
    float4 w = *(const float4*)(wrow+kc);
    #pragma unroll
    for (int tt=0; tt<8; ++tt){
      float4 x = *(const float4*)&xs[tt][kc];
      acc[tt] += w.x*x.x + w.y*x.y + w.z*x.z + w.w*x.w;
    }
  }
  float* Gx = is_dec ? GxD : GxE;
  #pragma unroll
  for (int tt=0; tt<8; ++tt){
    int t = t0+tt;
    if (t < T) Gx[(size_t)t*FOURE + r] = bias + acc[tt];
  }
}

// =================== B: single-XCD tagged ping-pong dataflow LSTM ===================
// Election (no timing assumptions): 512 blocks, 70KB LDS each -> exactly 2
// resident blocks/CU -> hard cap 64 blocks/XCD -> exactly 64 on block0's XCD.
// Block0 publishes its XCC_ID; blocks elsewhere exit; blocks on the chosen XCD
// take ranks 0..63 (atomicAdd) and are the workers. Workers never exit, so the
// chosen XCD accumulates exactly 64 workers. Transport: r8's proven tagged
// ping-pong inbox, now a SINGLE 8KB copy accessed with sc0 (L1-bypass,
// L2-coherent) -- all traffic stays inside the workers' shared L2.
__device__ __forceinline__ void load_weights(
    const float* __restrict__ Whh, float* __restrict__ wldsw, int j, int lane)
{
  #pragma unroll
  for (int gg=0; gg<4; ++gg){
    const float* wr = Whh + (size_t)(gg*E + j)*E;
    float4 a = *(const float4*)(wr + 4*lane);
    float4 b = *(const float4*)(wr + 4*lane + 256);
    float* dst = wldsw + (size_t)gg*E + (lane&7)*64 + (lane>>3)*4;
    *(float4*)dst      = a;   // wlds[g][q*64+4p+r] = W_row[32p+4q+r]
    *(float4*)(dst+32) = b;
  }
}

__global__ __launch_bounds__(512, 1) void lstm_kernel(
    const float* __restrict__ GxE, const float* __restrict__ GxD,
    const float* __restrict__ encWhh, const float* __restrict__ decWhh,
    unsigned long long* __restrict__ inbox, float* __restrict__ h_all,
    unsigned* __restrict__ regs)
{
  __shared__ float wlds[8][4][E];           // 64 KiB, wave-private slices
  __shared__ float hmir[2][576];            // padded h mirror
  __shared__ unsigned ltag[2];
  __shared__ int s_rank;
  const int tid  = threadIdx.x;
  const int lane = tid & 63, wave = tid >> 6;

  if (tid == 0){
    unsigned xcc;
    asm volatile("s_getreg_b32 %0, hwreg(HW_REG_XCC_ID)" : "=s"(xcc));
    xcc &= 15u;
    if (blockIdx.x == 0)
      __hip_atomic_store(&regs[0], 0x100u | xcc, __ATOMIC_RELAXED, __HIP_MEMORY_SCOPE_AGENT);
    unsigned ch = 0;
    for (int spin=0; spin<(1<<20); ++spin){
      ch = __hip_atomic_load(&regs[0], __ATOMIC_RELAXED, __HIP_MEMORY_SCOPE_AGENT);
      if (ch & 0x100u) break;
      __builtin_amdgcn_s_sleep(2);
    }
    int rank = -1;
    if ((ch & 0x100u) && ((ch & 15u) == xcc)){
      int r = (int)atomicAdd(&regs[1], 1u);   // device-scope; ranks 0..63
      if (r < NB) rank = r;
    }
    s_rank = rank;
    ltag[0] = 0u; ltag[1] = 0u;
  }
  __syncthreads();
  const int rank = s_rank;
  if (rank < 0) return;                       // not on chosen XCD -> exit

  const int g = lane >> 4, k = lane & 15;
  const int j = rank*8 + wave;                // h element owned by this wave
  const int row = g*E + j;
  float* wldsw = &wlds[wave][0][0];

  load_weights(encWhh, wldsw, j, lane);       // wave-private LDS region
  float cst = 0.f;

  for (int s=0; s<NSTEPS; ++s){
    if (s == SLEN){                           // enc -> dec boundary
      load_weights(decWhh, wldsw, j, lane);
      cst = 0.f;                              // reference resets cell state
    }
    const bool isdec = s >= SLEN;
    const int tloc = isdec ? (s - SLEN) : s;
    float gx = (isdec ? GxD : GxE)[(size_t)tloc*FOURE + row];

    float acc = 0.f;
    if (s > 0){
      const int buf = s & 1;
      if (wave == 0){
        const unsigned long long* hp = inbox + (size_t)buf*512 + 8*lane;
        uint4 a, b, cc, d;
        const unsigned t = (unsigned)s;
        for (int spin=0; spin<(1<<14); ++spin){
          asm volatile(
            "global_load_dwordx4 %0, %4, off sc0\n\t"
            "global_load_dwordx4 %1, %4, off offset:16 sc0\n\t"
            "global_load_dwordx4 %2, %4, off offset:32 sc0\n\t"
            "global_load_dwordx4 %3, %4, off offset:48 sc0\n\t"
            "s_waitcnt vmcnt(0)"
            : "=&v"(a), "=&v"(b), "=&v"(cc), "=&v"(d)
            : "v"(hp) : "memory");
          bool ok = (a.y==t)&&(a.w==t)&&(b.y==t)&&(b.w==t)
                 && (cc.y==t)&&(cc.w==t)&&(d.y==t)&&(d.w==t);
          if (__all(ok)) break;
          __builtin_amdgcn_s_sleep(1);
        }
        float* dm = &hmir[buf][8*lane + 4*(lane>>2)];
        float4 lo = make_float4(__uint_as_float(a.x),  __uint_as_float(a.z),
                                __uint_as_float(b.x),  __uint_as_float(b.z));
        float4 hi = make_float4(__uint_as_float(cc.x), __uint_as_float(cc.z),
                                __uint_as_float(d.x),  __uint_as_float(d.z));
        *(float4*)dm       = lo;
        *(float4*)(dm + 4) = hi;
        if (lane == 0)
          __hip_atomic_store(&ltag[buf], (unsigned)s, __ATOMIC_RELEASE, __HIP_MEMORY_SCOPE_WORKGROUP);
      }
      for (int spin=0; spin<(1<<18); ++spin){
        if (__hip_atomic_load(&ltag[buf], __ATOMIC_ACQUIRE, __HIP_MEMORY_SCOPE_WORKGROUP) == (unsigned)s) break;
      }
      // dot: lane (g,k) needs h[32k+4i+r] = hmir[buf][36k+4i+r]
      const float* hb = &hmir[buf][36*k];
      #pragma unroll
      for (int i=0;i<8;++i){
        float4 h4 = *(const float4*)(hb + 4*i);
        float4 wv = *(const float4*)&wldsw[(size_t)g*E + i*64 + 4*k];
        acc += wv.x*h4.x + wv.y*h4.y + wv.z*h4.z + wv.w*h4.w;
      }
      // reduce over the 16 k-slice lanes (bits 0..3)
      acc += __shfl_xor(acc,1); acc += __shfl_xor(acc,2);
      acc += __shfl_xor(acc,4); acc += __shfl_xor(acc,8);
    }

    float gv = acc + gx;
    // all-gather the 4 gate values (bits 4..5); torch order i,f,g,o
    float x1 = __shfl_xor(gv,16);
    float x2 = __shfl_xor(gv,32);
    float x3 = __shfl_xor(x1,32);
    float gi = (g==0)?gv:(g==1)?x1:(g==2)?x2:x3;
    float gf = (g==0)?x1:(g==1)?gv:(g==2)?x3:x2;
    float gg = (g==0)?x2:(g==1)?x3:(g==2)?gv:x1;
    float go = (g==0)?x3:(g==1)?x2:(g==2)?x1:gv;
    cst = sigf(gf)*cst + sigf(gi)*tanhf_fast(gg);
    float hnew = sigf(go)*tanhf_fast(cst);

    if (isdec && lane==0) h_all[(size_t)tloc*E + j] = hnew;

    // publish LAST: {tag s+1, h} into buffer (s+1)&1 (back-pressure proof: r8)
    if (lane==0){
      unsigned long long* dst = inbox + (size_t)((s+1)&1)*512 + j;
      uint2 pk; pk.x = __float_as_uint(hnew); pk.y = (unsigned)(s+1);
      asm volatile("global_store_dwordx2 %0, %1, off sc0" :: "v"(dst), "v"(pk) : "memory");
    }
  }
}

// =================== C1: logits GEMM + per-(t,chunk) softmax partials ===================
__global__ __launch_bounds__(128) void c1_kernel(
    const float* __restrict__ h_all, const float* __restrict__ W, const float* __restrict__ bvec,
    const int* __restrict__ tgt, float* __restrict__ pm, float* __restrict__ ps, float* __restrict__ tl)
{
  __shared__ float hst[32][E];
  const int tid  = threadIdx.x;
  const int wv   = tid >> 6, lane = tid & 63;
  const int chunk = blockIdx.x;
  const int t0    = blockIdx.y * 32;
  const int nt    = (t0 + 32 <= TLEN) ? 32 : (TLEN - t0);

  for (int idx = tid; idx < nt*(E/4); idx += 128)
    ((float4*)&hst[0][0])[idx] = ((const float4*)(h_all + (size_t)t0*E))[idx];
  __syncthreads();

  const int c0 = chunk*256 + tid;
  const int c1 = c0 + 128;
  const bool v0 = c0 < VT, v1 = c1 < VT;
  const float* w0 = W + (size_t)(v0 ? c0 : 0)*E;
  const float* w1 = W + (size_t)(v1 ? c1 : 0)*E;

  float acc0[32], acc1[32];
  #pragma unroll
  for (int i=0;i<32;++i){ acc0[i]=0.f; acc1[i]=0.f; }

  for (int kc=0; kc<E; kc+=4){
    float4 wa = *(const float4*)(w0+kc);
    float4 wb = *(const float4*)(w1+kc);
    #pragma unroll
    for (int tt=0; tt<32; ++tt){
      float4 h4 = *(const float4*)&hst[tt][kc];
      acc0[tt] += wa.x*h4.x + wa.y*h4.y + wa.z*h4.z + wa.w*h4.w;
      acc1[tt] += wb.x*h4.x + wb.y*h4.y + wb.z*h4.z + wb.w*h4.w;
    }
  }
  const float b0 = v0 ? bvec[c0] : 0.f;
  const float b1 = v1 ? bvec[c1] : 0.f;

  __syncthreads();
  float* red = &hst[0][0];

  #pragma unroll
  for (int tt=0; tt<32; ++tt){
    const bool act = tt < nt;
    float x0 = v0 ? acc0[tt]+b0 : -FLT_MAX;
    float x1 = v1 ? acc1[tt]+b1 : -FLT_MAX;
    float mx = fmaxf(x0,x1);
    #pragma unroll
    for (int off=1; off<64; off<<=1) mx = fmaxf(mx, __shfl_xor(mx, off));
    if (lane==0) red[wv] = mx;
    __syncthreads();
    mx = fmaxf(red[0], red[1]);
    float e = (v0 ? __expf(x0-mx) : 0.f) + (v1 ? __expf(x1-mx) : 0.f);
    #pragma unroll
    for (int off=1; off<64; off<<=1) e += __shfl_xor(e, off);
    if (lane==0) red[2+wv] = e;
    __syncthreads();
    float ssum = red[2] + red[3];
    if (act){
      int t = t0 + tt;
      if (tid==0){ pm[(size_t)chunk*TPAD + t] = mx; ps[(size_t)chunk*TPAD + t] = ssum; }
      int tok = (t < SLEN) ? tgt[t] : 1;
      if (v0 && c0==tok) tl[t] = x0;
      if (v1 && c1==tok) tl[t] = x1;
    }
    __syncthreads();
  }
}

// =================== C2: combine partials -> per-t loss -> sum ===================
__global__ __launch_bounds__(256) void c2_kernel(
    const float* __restrict__ pm, const float* __restrict__ ps, const float* __restrict__ tl,
    float* __restrict__ out)
{
  const int tid = threadIdx.x;
  float loss = 0.f;
  if (tid < TLEN){
    float m = -FLT_MAX, ssum = 0.f;
    for (int ch=0; ch<NCHUNK; ++ch){
      float mc = pm[(size_t)ch*TPAD + tid];
      float sc = ps[(size_t)ch*TPAD + tid];
      float nm = fmaxf(m, mc);
      ssum = ssum*__expf(m-nm) + sc*__expf(mc-nm);
      m = nm;
    }
    loss = (m + __logf(ssum)) - tl[tid];
  }
  __shared__ float red[4];
  #pragma unroll
  for (int off=1; off<64; off<<=1) loss += __shfl_xor(loss, off);
  if ((tid & 63)==0) red[tid>>6] = loss;
  __syncthreads();
  if (tid==0) out[0] = red[0]+red[1]+red[2]+red[3];
}

// =================== launch ===================
extern "C" void kernel_launch(void* const* d_in, const int* in_sizes, int n_in,
                              void* d_out, int out_size, void* d_ws, size_t ws_size,
                              hipStream_t stream)
{
  const int*   src    = (const int*)  d_in[0];
  const int*   tgt    = (const int*)  d_in[1];
  const float* Wx     = (const float*)d_in[2];
  const float* Wy     = (const float*)d_in[3];
  const float* encWih = (const float*)d_in[4];
  const float* encWhh = (const float*)d_in[5];
  const float* encBih = (const float*)d_in[6];
  const float* encBhh = (const float*)d_in[7];
  const float* decWih = (const float*)d_in[8];
  const float* decWhh = (const float*)d_in[9];
  const float* decBih = (const float*)d_in[10];
  const float* decBhh = (const float*)d_in[11];
  const float* Whr    = (const float*)d_in[12];
  const float* bhr    = (const float*)d_in[13];

  char* ws = (char*)d_ws;
  unsigned long long* inbox = (unsigned long long*)(ws + INBOX_OFF);
  unsigned* regs = (unsigned*)(ws + REG_OFF);
  float* GxE    = (float*)(ws + GXE_OFF);
  float* GxD    = (float*)(ws + GXD_OFF);
  float* hall   = (float*)(ws + HALL_OFF);   // aliases GxE rows 64..96 (dead in decode)
  float* pm     = (float*)(ws + PM_OFF);     // aliases GxE head (c1 runs after lstm)
  float* ps     = (float*)(ws + PS_OFF);
  float* tl     = (float*)(ws + TL_OFF);

  // zero inbox tags + election state (graph-replay safe)
  hipMemsetAsync(ws, 0, ZERO_BYTES, stream);

  dim3 ggrid(33, 8);
  gx_kernel<<<ggrid, 256, 0, stream>>>(src, tgt, Wx, Wy,
      encWih, encBih, encBhh, decWih, decBih, decBhh, GxE, GxD);

  lstm_kernel<<<NGRID, 512, 0, stream>>>(GxE, GxD, encWhh, decWhh, inbox, hall, regs);

  dim3 cgrid(NCHUNK, 5);
  c1_kernel<<<cgrid, 128, 0, stream>>>(hall, Whr, bhr, tgt, pm, ps, tl);

  c2_kernel<<<1, 256, 0, stream>>>(pm, ps, tl, (float*)d_out);
}

// Round 10
// 1117.902 us; speedup vs baseline: 845.1118x; 845.1118x over previous
//
#include <hip/hip_runtime.h>
#include <cfloat>
#include <cmath>

#define E      512
#define FOURE  2048
#define VT     50000
#define SLEN   128
#define TLEN   129            // decoder steps (targets + EOS)
#define NSTEPS 257
#define NB     64             // persistent LSTM blocks (64 <= 256 CUs -> co-resident)
#define NINBOX 32             // replicated inboxes; block bid polls inbox bid>>1
#define NCHUNK 196
#define TPAD   132

// ---- workspace layout (bytes); total 2,367,488 <= 2,597,572 proven (r1) ----
#define INBOX_OFF  0            // u64 inboxes[32][2][512] = 262144; memset 0 each call
#define GXE_OFF    262144       // 128*2048 f32 = 1048576 -> ends 1310720
#define PM_OFF     262144       //   alias GxE head (c1 runs after lstm): 103488
#define PS_OFF     365632       //   103488
#define TL_OFF     469120       //   129 f32 -> ends 469636
#define HALL_OFF   786432       //   alias GxE rows 64..96 (dead in decode): 264192 -> ends 1050624
#define GXD_OFF    1310720      // 129*2048 f32 = 1056768 -> ends 2367488

__device__ __forceinline__ float sigf(float x){ return 1.0f/(1.0f+__expf(-x)); }
__device__ __forceinline__ float tanhf_fast(float x){ return 2.f*sigf(2.f*x) - 1.f; }

// =================== A: Gx[t][r] = x_t @ W_ih^T + b_ih + b_hh ===================
__global__ __launch_bounds__(256) void gx_kernel(
    const int* __restrict__ src, const int* __restrict__ tgt,
    const float* __restrict__ Wx, const float* __restrict__ Wy,
    const float* __restrict__ encWih, const float* __restrict__ encBih, const float* __restrict__ encBhh,
    const float* __restrict__ decWih, const float* __restrict__ decBih, const float* __restrict__ decBhh,
    float* __restrict__ GxE, float* __restrict__ GxD)
{
  __shared__ float xs[8][E];
  const int tid  = threadIdx.x;
  const int tile = blockIdx.x;
  const bool is_dec = tile >= 16;
  const int t0 = is_dec ? (tile-16)*8 : tile*8;
  const int T  = is_dec ? TLEN : SLEN;

  for (int tt=0; tt<8; ++tt){
    int t = t0+tt;
    if (t < T){
      const float* xrow;
      if (is_dec) xrow = (t==0) ? (Wx + (size_t)1*E) : (Wy + (size_t)tgt[t-1]*E);
      else        xrow = Wx + (size_t)src[t]*E;
      xs[tt][tid]     = xrow[tid];
      xs[tt][tid+256] = xrow[tid+256];
    }
  }
  __syncthreads();

  const int r = blockIdx.y*256 + tid;
  const float* wrow = (is_dec ? decWih : encWih) + (size_t)r*E;
  const float  bias = is_dec ? (decBih[r]+decBhh[r]) : (encBih[r]+encBhh[r]);
  float acc[8];
  #pragma unroll
  for (int i=0;i<8;++i) acc[i]=0.f;

  for (int kc=0; kc<E; kc+=4){
    float4 w = *(const float4*)(wrow+kc);
    #pragma unroll
    for (int tt=0; tt<8; ++tt){
      float4 x = *(const float4*)&xs[tt][kc];
      acc[tt] += w.x*x.x + w.y*x.y + w.z*x.z + w.w*x.w;
    }
  }
  float* Gx = is_dec ? GxD : GxE;
  #pragma unroll
  for (int tt=0; tt<8; ++tt){
    int t = t0+tt;
    if (t < T) Gx[(size_t)t*FOURE + r] = bias + acc[tt];
  }
}

// =================== B: tagged ping-pong inbox dataflow LSTM (r8 + slice-poll) ===================
// 64 blocks x 8 waves; wave <-> h element j = bid*8+wave. lane: g=lane>>4
// (gate, torch order i,f,g,o), k=lane&15 (32-wide k slice).
// inbox slot = {tag:u32 hi, h bits:u32 lo}. End of step s publishes {s+1,h}
// into buffer (s+1)&1 of all 32 inboxes (lanes 0..31, 32 distinct lines).
// Back-pressure (r8 proof, re-derived for slice-poll): the block COLLECTIVELY
// verifies all 512 tags==s (each slot checked by exactly one wave, then
// __syncthreads) before any wave proceeds; publishing tag s happens after that
// wave's slice-loads of buffer (s+1)&1 (data dependency) -> overwriting buffer
// (s+1)&1 (tags s-1) at end of step s is safe. Exact-match monotone tags;
// bounded spins; inbox memset per call.
// Slice-poll: wave w polls slots [64w,64w+64) of its inbox (1 u64/lane),
// mirrors into LDS hmir[s&1] (padded idx c+4*(c>>5)); one __syncthreads
// replaces r8's wave0-poll + ltag release/acquire chain.
__device__ __forceinline__ void load_weights(
    const float* __restrict__ Whh, float* __restrict__ wldsw, int j, int lane)
{
  #pragma unroll
  for (int gg=0; gg<4; ++gg){
    const float* wr = Whh + (size_t)(gg*E + j)*E;
    float4 a = *(const float4*)(wr + 4*lane);
    float4 b = *(const float4*)(wr + 4*lane + 256);
    float* dst = wldsw + (size_t)gg*E + (lane&7)*64 + (lane>>3)*4;
    *(float4*)dst      = a;   // wlds[g][q*64+4p+r] = W_row[32p+4q+r]
    *(float4*)(dst+32) = b;
  }
}

__global__ __launch_bounds__(512, 1) void lstm_kernel(
    const float* __restrict__ GxE, const float* __restrict__ GxD,
    const float* __restrict__ encWhh, const float* __restrict__ decWhh,
    unsigned long long* __restrict__ inboxes, float* __restrict__ h_all)
{
  __shared__ float wlds[8][4][E];           // 64 KiB, wave-private slices
  __shared__ float hmir[2][576];            // padded h mirror
  const int tid  = threadIdx.x;
  const int lane = tid & 63, wave = tid >> 6, bid = blockIdx.x;
  const int g = lane >> 4, k = lane & 15;
  const int j = bid*8 + wave;
  const int row = g*E + j;
  const int slot  = wave*64 + lane;         // this thread's polled slot
  const int pslot = slot + 4*(slot>>5);     // padded LDS mirror index
  float* wldsw = &wlds[wave][0][0];
  const unsigned long long* myslot = inboxes + (size_t)(bid>>1)*1024 + slot;

  load_weights(encWhh, wldsw, j, lane);     // wave-private LDS region
  float cst = 0.f;

  for (int s=0; s<NSTEPS; ++s){
    if (s == SLEN){                         // enc -> dec boundary
      load_weights(decWhh, wldsw, j, lane); // wave-private region
      cst = 0.f;                            // reference resets cell state
    }
    const bool isdec = s >= SLEN;
    const int tloc = isdec ? (s - SLEN) : s;
    float gx = (isdec ? GxD : GxE)[(size_t)tloc*FOURE + row];

    float acc = 0.f;
    if (s > 0){
      const int buf = s & 1;
      // poll own slot of buffer buf until tag == s (1 u64 load per lane)
      unsigned long long hu;
      const unsigned long long* hp = myslot + (size_t)buf*512;
      for (int spin=0; spin<(1<<16); ++spin){
        hu = __hip_atomic_load(hp, __ATOMIC_RELAXED, __HIP_MEMORY_SCOPE_AGENT);
        if (__all((unsigned)(hu>>32) == (unsigned)s)) break;
        __builtin_amdgcn_s_sleep(1);
      }
      hmir[buf][pslot] = __uint_as_float((unsigned)hu);
      __syncthreads();                      // whole block: all 512 tags verified
      // dot: lane (g,k) needs h[32k+4i+r] = hmir[buf][36k+4i+r]
      const float* hb = &hmir[buf][36*k];
      #pragma unroll
      for (int i=0;i<8;++i){
        float4 h4 = *(const float4*)(hb + 4*i);
        float4 wv = *(const float4*)&wldsw[(size_t)g*E + i*64 + 4*k];
        acc += wv.x*h4.x + wv.y*h4.y + wv.z*h4.z + wv.w*h4.w;
      }
      // reduce over the 16 k-slice lanes (bits 0..3)
      acc += __shfl_xor(acc,1); acc += __shfl_xor(acc,2);
      acc += __shfl_xor(acc,4); acc += __shfl_xor(acc,8);
    }

    float gv = acc + gx;
    // all-gather the 4 gate values (bits 4..5)
    float x1 = __shfl_xor(gv,16);
    float x2 = __shfl_xor(gv,32);
    float x3 = __shfl_xor(x1,32);
    float gi = (g==0)?gv:(g==1)?x1:(g==2)?x2:x3;
    float gf = (g==0)?x1:(g==1)?gv:(g==2)?x3:x2;
    float gg = (g==0)?x2:(g==1)?x3:(g==2)?gv:x1;
    float go = (g==0)?x3:(g==1)?x2:(g==2)?x1:gv;
    cst = sigf(gf)*cst + sigf(gi)*tanhf_fast(gg);
    float hnew = sigf(go)*tanhf_fast(cst);

    // publish FIRST (critical path): {s+1,h} -> buffer (s+1)&1 of all 32 inboxes
    unsigned long long pk = ((unsigned long long)(unsigned)(s+1) << 32)
                          |  (unsigned long long)__float_as_uint(hnew);
    if (lane < NINBOX)
      __hip_atomic_store(inboxes + (size_t)lane*1024 + (size_t)((s+1)&1)*512 + j,
                         pk, __ATOMIC_RELAXED, __HIP_MEMORY_SCOPE_AGENT);
    if (isdec && lane==0) h_all[(size_t)tloc*E + j] = hnew;
  }
}

// =================== C1: logits GEMM + per-(t,chunk) softmax partials ===================
__global__ __launch_bounds__(128) void c1_kernel(
    const float* __restrict__ h_all, const float* __restrict__ W, const float* __restrict__ bvec,
    const int* __restrict__ tgt, float* __restrict__ pm, float* __restrict__ ps, float* __restrict__ tl)
{
  __shared__ float hst[32][E];
  const int tid  = threadIdx.x;
  const int wv   = tid >> 6, lane = tid & 63;
  const int chunk = blockIdx.x;
  const int t0    = blockIdx.y * 32;
  const int nt    = (t0 + 32 <= TLEN) ? 32 : (TLEN - t0);

  for (int idx = tid; idx < nt*(E/4); idx += 128)
    ((float4*)&hst[0][0])[idx] = ((const float4*)(h_all + (size_t)t0*E))[idx];
  __syncthreads();

  const int c0 = chunk*256 + tid;
  const int c1 = c0 + 128;
  const bool v0 = c0 < VT, v1 = c1 < VT;
  const float* w0 = W + (size_t)(v0 ? c0 : 0)*E;
  const float* w1 = W + (size_t)(v1 ? c1 : 0)*E;

  float acc0[32], acc1[32];
  #pragma unroll
  for (int i=0;i<32;++i){ acc0[i]=0.f; acc1[i]=0.f; }

  for (int kc=0; kc<E; kc+=4){
    float4 wa = *(const float4*)(w0+kc);
    float4 wb = *(const float4*)(w1+kc);
    #pragma unroll
    for (int tt=0; tt<32; ++tt){
      float4 h4 = *(const float4*)&hst[tt][kc];
      acc0[tt] += wa.x*h4.x + wa.y*h4.y + wa.z*h4.z + wa.w*h4.w;
      acc1[tt] += wb.x*h4.x + wb.y*h4.y + wb.z*h4.z + wb.w*h4.w;
    }
  }
  const float b0 = v0 ? bvec[c0] : 0.f;
  const float b1 = v1 ? bvec[c1] : 0.f;

  __syncthreads();
  float* red = &hst[0][0];

  #pragma unroll
  for (int tt=0; tt<32; ++tt){
    const bool act = tt < nt;
    float x0 = v0 ? acc0[tt]+b0 : -FLT_MAX;
    float x1 = v1 ? acc1[tt]+b1 : -FLT_MAX;
    float mx = fmaxf(x0,x1);
    #pragma unroll
    for (int off=1; off<64; off<<=1) mx = fmaxf(mx, __shfl_xor(mx, off));
    if (lane==0) red[wv] = mx;
    __syncthreads();
    mx = fmaxf(red[0], red[1]);
    float e = (v0 ? __expf(x0-mx) : 0.f) + (v1 ? __expf(x1-mx) : 0.f);
    #pragma unroll
    for (int off=1; off<64; off<<=1) e += __shfl_xor(e, off);
    if (lane==0) red[2+wv] = e;
    __syncthreads();
    float ssum = red[2] + red[3];
    if (act){
      int t = t0 + tt;
      if (tid==0){ pm[(size_t)chunk*TPAD + t] = mx; ps[(size_t)chunk*TPAD + t] = ssum; }
      int tok = (t < SLEN) ? tgt[t] : 1;
      if (v0 && c0==tok) tl[t] = x0;
      if (v1 && c1==tok) tl[t] = x1;
    }
    __syncthreads();
  }
}

// =================== C2: combine partials -> per-t loss -> sum ===================
__global__ __launch_bounds__(256) void c2_kernel(
    const float* __restrict__ pm, const float* __restrict__ ps, const float* __restrict__ tl,
    float* __restrict__ out)
{
  const int tid = threadIdx.x;
  float loss = 0.f;
  if (tid < TLEN){
    float m = -FLT_MAX, ssum = 0.f;
    for (int ch=0; ch<NCHUNK; ++ch){
      float mc = pm[(size_t)ch*TPAD + tid];
      float sc = ps[(size_t)ch*TPAD + tid];
      float nm = fmaxf(m, mc);
      ssum = ssum*__expf(m-nm) + sc*__expf(mc-nm);
      m = nm;
    }
    loss = (m + __logf(ssum)) - tl[tid];
  }
  __shared__ float red[4];
  #pragma unroll
  for (int off=1; off<64; off<<=1) loss += __shfl_xor(loss, off);
  if ((tid & 63)==0) red[tid>>6] = loss;
  __syncthreads();
  if (tid==0) out[0] = red[0]+red[1]+red[2]+red[3];
}

// =================== launch ===================
extern "C" void kernel_launch(void* const* d_in, const int* in_sizes, int n_in,
                              void* d_out, int out_size, void* d_ws, size_t ws_size,
                              hipStream_t stream)
{
  const int*   src    = (const int*)  d_in[0];
  const int*   tgt    = (const int*)  d_in[1];
  const float* Wx     = (const float*)d_in[2];
  const float* Wy     = (const float*)d_in[3];
  const float* encWih = (const float*)d_in[4];
  const float* encWhh = (const float*)d_in[5];
  const float* encBih = (const float*)d_in[6];
  const float* encBhh = (const float*)d_in[7];
  const float* decWih = (const float*)d_in[8];
  const float* decWhh = (const float*)d_in[9];
  const float* decBih = (const float*)d_in[10];
  const float* decBhh = (const float*)d_in[11];
  const float* Whr    = (const float*)d_in[12];
  const float* bhr    = (const float*)d_in[13];

  char* ws = (char*)d_ws;
  unsigned long long* inboxes = (unsigned long long*)(ws + INBOX_OFF);
  float* GxE    = (float*)(ws + GXE_OFF);
  float* GxD    = (float*)(ws + GXD_OFF);
  float* hall   = (float*)(ws + HALL_OFF);   // aliases GxE rows 64..96 (dead in decode)
  float* pm     = (float*)(ws + PM_OFF);     // aliases GxE head (c1 runs after lstm)
  float* ps     = (float*)(ws + PS_OFF);
  float* tl     = (float*)(ws + TL_OFF);

  // reset inbox tags (graph-replay safe: stale tags from prior call would race)
  hipMemsetAsync(ws + INBOX_OFF, 0, NINBOX*1024*8, stream);

  dim3 ggrid(33, 8);
  gx_kernel<<<ggrid, 256, 0, stream>>>(src, tgt, Wx, Wy,
      encWih, encBih, encBhh, decWih, decBih, decBhh, GxE, GxD);

  lstm_kernel<<<NB, 512, 0, stream>>>(GxE, GxD, encWhh, decWhh, inboxes, hall);

  dim3 cgrid(NCHUNK, 5);
  c1_kernel<<<cgrid, 128, 0, stream>>>(hall, Whr, bhr, tgt, pm, ps, tl);

  c2_kernel<<<1, 256, 0, stream>>>(pm, ps, tl, (float*)d_out);
}